// Round 14
// baseline (880.001 us; speedup 1.0000x reference)
//
#include <hip/hip_runtime.h>
#include <math.h>

constexpr int C_IN  = 128;
constexpr int C_HID = 128;
constexpr int C_OUT = 64;
constexpr int NBLK  = 1024;   // persistent grid (4 blocks/CU on 256 CUs)
constexpr int FB    = 448;    // blocks doing CSR-fill in phase 3 (rest: gemm1)

typedef short bf8   __attribute__((ext_vector_type(8)));   // 8 bf16
typedef float f32x4 __attribute__((ext_vector_type(4)));   // MFMA acc

__device__ __forceinline__ int wave_incl_scan(int v, int lane) {
    #pragma unroll
    for (int off = 1; off < 64; off <<= 1) {
        int u = __shfl_up(v, off, 64);
        if (lane >= off) v += u;
    }
    return v;
}
__device__ __forceinline__ short b16(float f) {
    unsigned int u = __float_as_uint(f);
    u += 0x7FFFu + ((u >> 16) & 1u);
    return (short)(u >> 16);
}
__device__ __forceinline__ unsigned int bpack(float a, float b) {
    unsigned int ua = __float_as_uint(a), ub = __float_as_uint(b);
    ua += 0x7FFFu + ((ua >> 16) & 1u);
    ub += 0x7FFFu + ((ub >> 16) & 1u);
    return (ua >> 16) | (ub & 0xFFFF0000u);
}
__device__ __forceinline__ void acc8(float* a, const uint4 v) {
    a[0] += __uint_as_float(v.x << 16);
    a[1] += __uint_as_float(v.x & 0xFFFF0000u);
    a[2] += __uint_as_float(v.y << 16);
    a[3] += __uint_as_float(v.y & 0xFFFF0000u);
    a[4] += __uint_as_float(v.z << 16);
    a[5] += __uint_as_float(v.z & 0xFFFF0000u);
    a[6] += __uint_as_float(v.w << 16);
    a[7] += __uint_as_float(v.w & 0xFFFF0000u);
}

// Grid barrier: monotonic arrive counter, device-scope atomics.
__device__ __forceinline__ void gbar(int* arrive, int target) {
    __syncthreads();
    if (threadIdx.x == 0) {
        __threadfence();
        atomicAdd(arrive, 1);
        int guard = 0;
        while (atomicAdd(arrive, 0) < target && ++guard < (1 << 22))
            __builtin_amdgcn_s_sleep(8);
        __threadfence();
    }
    __syncthreads();
}

// zero cnt + barrier/ticket counters (runs each call; immune to 0xAA poison)
__global__ __launch_bounds__(256) void k_init(int* __restrict__ cnt, int n,
                                              int* __restrict__ bar) {
    int i = blockIdx.x * 256 + threadIdx.x;
    int n4 = (n + 3) / 4;
    if (i < n4) reinterpret_cast<int4*>(cnt)[i] = make_int4(0, 0, 0, 0);
    if (blockIdx.x == 0 && threadIdx.x < 4) bar[threadIdx.x] = 0;
}

__global__ __launch_bounds__(256, 4) void k_fused(
    const int* __restrict__ src, const int* __restrict__ dst, int e,
    const float* __restrict__ x, const float* __restrict__ W1,
    const float* __restrict__ b1, const float* __restrict__ W2,
    const float* __restrict__ b2,
    int* __restrict__ cnt, int* __restrict__ slot,
    int* __restrict__ rowstart, int* __restrict__ blocksum,
    int* __restrict__ blockoff, int* __restrict__ bar,
    unsigned short* __restrict__ nbr, unsigned short* __restrict__ h1b,
    unsigned short* __restrict__ actb, unsigned short* __restrict__ h2b,
    float* __restrict__ dinv, float* __restrict__ outb, int n) {
    __shared__ short wf[8 * 4 * 64 * 8];   // 32 KiB (W1 frags; W2 reuses half)
    __shared__ int swave[4];
    __shared__ int amLast;
    const int tid = threadIdx.x;
    const int bid = blockIdx.x;
    int* arrive  = bar + 0;
    int* depart  = bar + 1;
    int* ticket2 = bar + 2;
    const int NB = (n + 1023) >> 10;       // scan blocks (49)
    const int nCU = (e + 1023) >> 10;      // 1024-edge units (782)
    const int nT  = (n + 63) >> 6;         // 64-row gemm tiles (782)

    // ---------- phase 1: count + slot ----------
    for (int u = bid; u < nCU; u += NBLK) {
        int base = u * 1024 + tid * 4;
        if (base + 3 < e) {
            int4 d4 = *reinterpret_cast<const int4*>(dst + base);
            int4 s4;
            s4.x = atomicAdd(&cnt[d4.x], 1);
            s4.y = atomicAdd(&cnt[d4.y], 1);
            s4.z = atomicAdd(&cnt[d4.z], 1);
            s4.w = atomicAdd(&cnt[d4.w], 1);
            *reinterpret_cast<int4*>(slot + base) = s4;
        } else if (base < e) {
            for (int q = base; q < e; ++q) slot[q] = atomicAdd(&cnt[dst[q]], 1);
        }
    }
    gbar(arrive, 1 * NBLK);

    // ---------- phase 2: scan (block-local rowstart + dinv; last scans blockoff) ----------
    if (bid < NB) {
        const int lane = tid & 63, w = tid >> 6;
        const int idx = bid * 1024 + tid * 4;
        int4 c = make_int4(0, 0, 0, 0);
        if (idx + 3 < n) {
            c = *reinterpret_cast<const int4*>(cnt + idx);
        } else if (idx < n) {
            c.x = cnt[idx];
            if (idx + 1 < n) c.y = cnt[idx + 1];
            if (idx + 2 < n) c.z = cnt[idx + 2];
            if (idx + 3 < n) c.w = cnt[idx + 3];
        }
        if (idx + 0 < n) dinv[idx + 0] = rsqrtf((float)(c.x + 1));
        if (idx + 1 < n) dinv[idx + 1] = rsqrtf((float)(c.y + 1));
        if (idx + 2 < n) dinv[idx + 2] = rsqrtf((float)(c.z + 1));
        if (idx + 3 < n) dinv[idx + 3] = rsqrtf((float)(c.w + 1));

        const int s4v = c.x + c.y + c.z + c.w;
        const int incl = wave_incl_scan(s4v, lane);
        if (lane == 63) swave[w] = incl;
        __syncthreads();
        int base2 = incl - s4v;
        #pragma unroll
        for (int j = 0; j < 4; ++j) if (j < w) base2 += swave[j];

        if (idx + 3 < n) {
            int4 o;
            o.x = base2;
            o.y = base2 + c.x;
            o.z = base2 + c.x + c.y;
            o.w = base2 + c.x + c.y + c.z;
            *reinterpret_cast<int4*>(rowstart + idx) = o;
        } else if (idx < n) {
            int acc = base2;
            rowstart[idx] = acc; acc += c.x;
            if (idx + 1 < n) { rowstart[idx + 1] = acc; acc += c.y; }
            if (idx + 2 < n) { rowstart[idx + 2] = acc; acc += c.z; }
            if (idx + 3 < n) { rowstart[idx + 3] = acc; }
        }

        if (tid == 0) {
            int tot = swave[0] + swave[1] + swave[2] + swave[3];
            blocksum[bid] = tot;
            if (bid == NB - 1) rowstart[n] = tot;   // block-local end
            __threadfence();
            amLast = (atomicAdd(ticket2, 1) == NB - 1);
        }
        __syncthreads();
        if (amLast && tid < 64) {
            __threadfence();
            volatile int* bs = blocksum;
            int v = (tid < NB) ? bs[tid] : 0;
            int incl2 = wave_incl_scan(v, tid);
            if (tid < NB) blockoff[tid] = incl2 - v;
        }
    }
    gbar(arrive, 2 * NBLK);

    // ---------- phase 3: fill (blocks [0,FB)) || gemm1 (blocks [FB,NBLK)) ----------
    if (bid < FB) {
        for (int u = bid; u < nCU; u += FB) {
            int base = u * 1024 + tid * 4;
            if (base + 3 < e) {
                int4 d4 = *reinterpret_cast<const int4*>(dst + base);
                int4 s4 = *reinterpret_cast<const int4*>(src + base);
                int4 t4 = *reinterpret_cast<const int4*>(slot + base);
                nbr[rowstart[d4.x] + blockoff[d4.x >> 10] + t4.x] = (unsigned short)s4.x;
                nbr[rowstart[d4.y] + blockoff[d4.y >> 10] + t4.y] = (unsigned short)s4.y;
                nbr[rowstart[d4.z] + blockoff[d4.z >> 10] + t4.z] = (unsigned short)s4.z;
                nbr[rowstart[d4.w] + blockoff[d4.w >> 10] + t4.w] = (unsigned short)s4.w;
            } else if (base < e) {
                for (int q = base; q < e; ++q) {
                    int d = dst[q];
                    nbr[rowstart[d] + blockoff[d >> 10] + slot[q]] = (unsigned short)src[q];
                }
            }
        }
    } else {
        for (int i = tid; i < 2048; i += 256) {
            const int l = i & 63, kt = (i >> 6) & 3, ct = i >> 8;
            const int krow = kt * 32 + ((l >> 4) << 3);
            const int col  = ct * 16 + (l & 15);
            const float* wp = W1 + (size_t)krow * C_HID + col;
            uint4 u;
            u.x = bpack(wp[0 * C_HID], wp[1 * C_HID]);
            u.y = bpack(wp[2 * C_HID], wp[3 * C_HID]);
            u.z = bpack(wp[4 * C_HID], wp[5 * C_HID]);
            u.w = bpack(wp[6 * C_HID], wp[7 * C_HID]);
            reinterpret_cast<uint4*>(wf)[i] = u;
        }
        __syncthreads();
        const int l = tid & 63, w = tid >> 6;
        const bf8* bw = reinterpret_cast<const bf8*>(wf);
        for (int t = bid - FB; t < nT; t += (NBLK - FB)) {
            const int row0 = t * 64 + w * 16;
            int arow = row0 + (l & 15);
            if (arow >= n) arow = n - 1;
            const float* xr = x + (size_t)arow * C_IN + ((l >> 4) << 3);
            bf8 a[4];
            #pragma unroll
            for (int kt = 0; kt < 4; ++kt) {
                float4 p0 = *reinterpret_cast<const float4*>(xr + kt * 32);
                float4 p1 = *reinterpret_cast<const float4*>(xr + kt * 32 + 4);
                bf8 tt;
                tt[0] = b16(p0.x); tt[1] = b16(p0.y); tt[2] = b16(p0.z); tt[3] = b16(p0.w);
                tt[4] = b16(p1.x); tt[5] = b16(p1.y); tt[6] = b16(p1.z); tt[7] = b16(p1.w);
                a[kt] = tt;
            }
            f32x4 acc[8];
            #pragma unroll
            for (int ct = 0; ct < 8; ++ct) acc[ct] = (f32x4){0.f, 0.f, 0.f, 0.f};
            #pragma unroll
            for (int kt = 0; kt < 4; ++kt)
                #pragma unroll
                for (int ct = 0; ct < 8; ++ct)
                    acc[ct] = __builtin_amdgcn_mfma_f32_16x16x32_bf16(
                        a[kt], bw[(ct * 4 + kt) * 64 + l], acc[ct], 0, 0, 0);
            const int rbase = row0 + ((l >> 4) << 2);
            float dv[4];
            #pragma unroll
            for (int r = 0; r < 4; ++r) {
                int rr = rbase + r;
                dv[r] = (rr < n) ? dinv[rr] : 0.f;
            }
            #pragma unroll
            for (int ct = 0; ct < 8; ++ct) {
                const int col = ct * 16 + (l & 15);
                #pragma unroll
                for (int r = 0; r < 4; ++r) {
                    int rr = rbase + r;
                    if (rr < n)
                        h1b[(size_t)rr * C_HID + col] = (unsigned short)b16(acc[ct][r] * dv[r]);
                }
            }
        }
    }
    gbar(arrive, 3 * NBLK);

    // ---------- phase 4: agg1 (16 thr/node, uint4 gathers) ----------
    {
        const uint4* h1v = reinterpret_cast<const uint4*>(h1b);
        uint4* actv = reinterpret_cast<uint4*>(actb);
        const int c8 = tid & 15, grp = tid >> 4;
        const int nU = (n + 15) >> 4;
        const float4 bb0 = reinterpret_cast<const float4*>(b1)[2 * c8 + 0];
        const float4 bb1 = reinterpret_cast<const float4*>(b1)[2 * c8 + 1];
        for (int u = bid; u < nU; u += NBLK) {
            int node = u * 16 + grp;
            if (node >= n) continue;
            float a8[8] = {0.f, 0.f, 0.f, 0.f, 0.f, 0.f, 0.f, 0.f};
            acc8(a8, h1v[(size_t)node * 16 + c8]);
            int j   = rowstart[node]     + blockoff[node >> 10];
            int end = rowstart[node + 1] + blockoff[(node + 1) >> 10];
            for (; j + 1 < end; j += 2) {
                int s0 = nbr[j], s1 = nbr[j + 1];
                uint4 v0 = h1v[(size_t)s0 * 16 + c8];
                uint4 v1 = h1v[(size_t)s1 * 16 + c8];
                acc8(a8, v0); acc8(a8, v1);
            }
            if (j < end) acc8(a8, h1v[(size_t)nbr[j] * 16 + c8]);
            const float sc = dinv[node];
            uint4 p;
            p.x = bpack(fmaxf(sc * a8[0] + bb0.x, 0.f), fmaxf(sc * a8[1] + bb0.y, 0.f));
            p.y = bpack(fmaxf(sc * a8[2] + bb0.z, 0.f), fmaxf(sc * a8[3] + bb0.w, 0.f));
            p.z = bpack(fmaxf(sc * a8[4] + bb1.x, 0.f), fmaxf(sc * a8[5] + bb1.y, 0.f));
            p.w = bpack(fmaxf(sc * a8[6] + bb1.z, 0.f), fmaxf(sc * a8[7] + bb1.w, 0.f));
            actv[(size_t)node * 16 + c8] = p;
        }
    }
    gbar(arrive, 4 * NBLK);

    // ---------- phase 5: gemm2 ----------
    {
        for (int i = tid; i < 1024; i += 256) {
            const int l = i & 63, kt = (i >> 6) & 3, ct = i >> 8;
            const int krow = kt * 32 + ((l >> 4) << 3);
            const int col  = ct * 16 + (l & 15);
            const float* wp = W2 + (size_t)krow * C_OUT + col;
            uint4 u;
            u.x = bpack(wp[0 * C_OUT], wp[1 * C_OUT]);
            u.y = bpack(wp[2 * C_OUT], wp[3 * C_OUT]);
            u.z = bpack(wp[4 * C_OUT], wp[5 * C_OUT]);
            u.w = bpack(wp[6 * C_OUT], wp[7 * C_OUT]);
            reinterpret_cast<uint4*>(wf)[i] = u;
        }
        __syncthreads();
        const int l = tid & 63, w = tid >> 6;
        const bf8* bw = reinterpret_cast<const bf8*>(wf);
        for (int t = bid; t < nT; t += NBLK) {
            const int row0 = t * 64 + w * 16;
            int arow = row0 + (l & 15);
            if (arow >= n) arow = n - 1;
            const unsigned short* ar = actb + (size_t)arow * C_HID + ((l >> 4) << 3);
            bf8 a[4];
            #pragma unroll
            for (int kt = 0; kt < 4; ++kt)
                a[kt] = *reinterpret_cast<const bf8*>(ar + kt * 32);
            f32x4 acc[4];
            #pragma unroll
            for (int ct = 0; ct < 4; ++ct) acc[ct] = (f32x4){0.f, 0.f, 0.f, 0.f};
            #pragma unroll
            for (int kt = 0; kt < 4; ++kt)
                #pragma unroll
                for (int ct = 0; ct < 4; ++ct)
                    acc[ct] = __builtin_amdgcn_mfma_f32_16x16x32_bf16(
                        a[kt], bw[(ct * 4 + kt) * 64 + l], acc[ct], 0, 0, 0);
            const int rbase = row0 + ((l >> 4) << 2);
            float dv[4];
            #pragma unroll
            for (int r = 0; r < 4; ++r) {
                int rr = rbase + r;
                dv[r] = (rr < n) ? dinv[rr] : 0.f;
            }
            #pragma unroll
            for (int ct = 0; ct < 4; ++ct) {
                const int col = ct * 16 + (l & 15);
                #pragma unroll
                for (int r = 0; r < 4; ++r) {
                    int rr = rbase + r;
                    if (rr < n)
                        h2b[(size_t)rr * C_OUT + col] = (unsigned short)b16(acc[ct][r] * dv[r]);
                }
            }
        }
    }
    gbar(arrive, 5 * NBLK);

    // ---------- phase 6: agg2 ----------
    {
        const uint4* h2v = reinterpret_cast<const uint4*>(h2b);
        const int lane8 = tid & 7, grp = tid >> 3;
        const int nU = (n + 31) >> 5;
        const float4 c0 = reinterpret_cast<const float4*>(b2)[2 * lane8 + 0];
        const float4 c1 = reinterpret_cast<const float4*>(b2)[2 * lane8 + 1];
        for (int u = bid; u < nU; u += NBLK) {
            int node = u * 32 + grp;
            if (node >= n) continue;
            float a8[8] = {0.f, 0.f, 0.f, 0.f, 0.f, 0.f, 0.f, 0.f};
            acc8(a8, h2v[(size_t)node * 8 + lane8]);
            int j   = rowstart[node]     + blockoff[node >> 10];
            int end = rowstart[node + 1] + blockoff[(node + 1) >> 10];
            for (; j + 1 < end; j += 2) {
                int s0 = nbr[j], s1 = nbr[j + 1];
                uint4 v0 = h2v[(size_t)s0 * 8 + lane8];
                uint4 v1 = h2v[(size_t)s1 * 8 + lane8];
                acc8(a8, v0); acc8(a8, v1);
            }
            if (j < end) acc8(a8, h2v[(size_t)nbr[j] * 8 + lane8]);
            const float s = dinv[node];
            float4 o0, o1;
            o0.x = s * a8[0] + c0.x; o0.y = s * a8[1] + c0.y;
            o0.z = s * a8[2] + c0.z; o0.w = s * a8[3] + c0.w;
            o1.x = s * a8[4] + c1.x; o1.y = s * a8[5] + c1.y;
            o1.z = s * a8[6] + c1.z; o1.w = s * a8[7] + c1.w;
            reinterpret_cast<float4*>(outb)[node * 16 + 2 * lane8 + 0] = o0;
            reinterpret_cast<float4*>(outb)[node * 16 + 2 * lane8 + 1] = o1;
        }
    }

    // ---------- final barrier + counter reset (replay idempotence) ----------
    __syncthreads();
    if (tid == 0) {
        __threadfence();
        atomicAdd(arrive, 1);
        int guard = 0;
        while (atomicAdd(arrive, 0) < 6 * NBLK && ++guard < (1 << 22))
            __builtin_amdgcn_s_sleep(8);
        if (atomicAdd(depart, 1) == NBLK - 1) {
            atomicExch(arrive, 0);
            atomicExch(depart, 0);
            atomicExch(ticket2, 0);
        }
    }
}

extern "C" void kernel_launch(void* const* d_in, const int* in_sizes, int n_in,
                              void* d_out, int out_size, void* d_ws, size_t ws_size,
                              hipStream_t stream) {
    const float* x  = (const float*)d_in[0];
    const int*   ei = (const int*)d_in[1];
    const float* W1 = (const float*)d_in[2];
    const float* b1 = (const float*)d_in[3];
    const float* W2 = (const float*)d_in[4];
    const float* b2 = (const float*)d_in[5];

    const int n = in_sizes[0] / C_IN;   // 50000 (<=65536: u16 nbr, 2-level scan)
    const int e = in_sizes[1] / 2;      // 800000
    const int* src = ei;
    const int* dst = ei + e;

    // Workspace layout (non-overlapping):
    //   [0, 256K)      dinv
    //   [256K, 512K)   cnt (n ints)
    //   [512K, 768K)   rowstart (n+1 ints, padded)
    //   [768K, +4K)    blocksum ; [772K, +4K) blockoff ; [776K, +16) bar
    //   [1M, 4.2M)     slot
    //   [5M, 6.6M)     nbr (u16)
    //   [8M, 20.8M)    h1b ; [21M, 33.8M) actb ; [34M, 40.4M) h2b
    char* ws = (char*)d_ws;
    float* dinv     = (float*)(ws);
    int*   cnt      = (int*)  (ws + (1u << 18));
    int*   rowstart = (int*)  (ws + (2u << 18));
    int*   blocksum = (int*)  (ws + (3u << 18));
    int*   blockoff = (int*)  (ws + (3u << 18) + 4096);
    int*   bar      = (int*)  (ws + (3u << 18) + 8192);
    int*   slot     = (int*)  (ws + (1u << 20));
    unsigned short* nbr  = (unsigned short*)(ws + (5u << 20));
    unsigned short* h1b  = (unsigned short*)(ws + (8u << 20));
    unsigned short* actb = (unsigned short*)(ws + (21u << 20));
    unsigned short* h2b  = (unsigned short*)(ws + (34u << 20));
    float* outb     = (float*)d_out;

    const int nz = ((n + 3) / 4 + 255) / 256;
    k_init <<<nz, 256, 0, stream>>>(cnt, n, bar);
    k_fused<<<NBLK, 256, 0, stream>>>(src, dst, e, x, W1, b1, W2, b2,
                                      cnt, slot, rowstart, blocksum, blockoff, bar,
                                      nbr, h1b, actb, h2b, dinv, outb, n);
}

// Round 15
// 132.130 us; speedup vs baseline: 6.6601x; 6.6601x over previous
//
#include <hip/hip_runtime.h>
#include <math.h>

constexpr int C_IN  = 128;
constexpr int C_HID = 128;
constexpr int C_OUT = 64;

typedef short bf8   __attribute__((ext_vector_type(8)));   // 8 bf16 (4 VGPRs)
typedef float f32x4 __attribute__((ext_vector_type(4)));   // MFMA acc

__device__ __forceinline__ int wave_incl_scan(int v, int lane) {
    #pragma unroll
    for (int off = 1; off < 64; off <<= 1) {
        int u = __shfl_up(v, off, 64);
        if (lane >= off) v += u;
    }
    return v;
}
__device__ __forceinline__ short b16(float f) {
    unsigned int u = __float_as_uint(f);
    u += 0x7FFFu + ((u >> 16) & 1u);
    return (short)(u >> 16);
}
__device__ __forceinline__ unsigned int bpack(float a, float b) {
    unsigned int ua = __float_as_uint(a), ub = __float_as_uint(b);
    ua += 0x7FFFu + ((ua >> 16) & 1u);
    ub += 0x7FFFu + ((ub >> 16) & 1u);
    return (ua >> 16) | (ub & 0xFFFF0000u);
}
__device__ __forceinline__ void acc8(float* a, const uint4 v) {
    a[0] += __uint_as_float(v.x << 16);
    a[1] += __uint_as_float(v.x & 0xFFFF0000u);
    a[2] += __uint_as_float(v.y << 16);
    a[3] += __uint_as_float(v.y & 0xFFFF0000u);
    a[4] += __uint_as_float(v.z << 16);
    a[5] += __uint_as_float(v.z & 0xFFFF0000u);
    a[6] += __uint_as_float(v.w << 16);
    a[7] += __uint_as_float(v.w & 0xFFFF0000u);
}

__global__ __launch_bounds__(256) void k_zero(int* __restrict__ p, int n4) {
    int i = blockIdx.x * 256 + threadIdx.x;
    if (i < n4) reinterpret_cast<int4*>(p)[i] = make_int4(0, 0, 0, 0);
}

// slot[i] = within-row position; cnt[d] = degree. 4 edges/thread.
__global__ __launch_bounds__(256) void k_count2(const int* __restrict__ dst, int e,
                                                int* __restrict__ cnt,
                                                int* __restrict__ slot) {
    int i = blockIdx.x * 256 + threadIdx.x;
    int base = i * 4;
    if (base >= e) return;
    if (base + 3 < e) {
        int4 d4 = *reinterpret_cast<const int4*>(dst + base);
        int4 s4;
        s4.x = atomicAdd(&cnt[d4.x], 1);
        s4.y = atomicAdd(&cnt[d4.y], 1);
        s4.z = atomicAdd(&cnt[d4.z], 1);
        s4.w = atomicAdd(&cnt[d4.w], 1);
        *reinterpret_cast<int4*>(slot + base) = s4;
    } else {
        for (int q = base; q < e; ++q) slot[q] = atomicAdd(&cnt[dst[q]], 1);
    }
}

// Fused scan: block-local rowstart + blocksum + dinv; last-arriving block
// wave-scans block sums into blockoff. Consumers add blockoff[node>>10].
__global__ __launch_bounds__(256) void k_scanAB(const int* __restrict__ cnt, int n,
                                                int* __restrict__ rowstart,
                                                int* __restrict__ blocksum,
                                                int* __restrict__ blockoff,
                                                int* __restrict__ ticket,
                                                float* __restrict__ dinv) {
    __shared__ int swave[4];
    __shared__ int amLast;
    const int tid = threadIdx.x, lane = tid & 63, w = tid >> 6;
    const int idx = blockIdx.x * 1024 + tid * 4;
    int4 c = make_int4(0, 0, 0, 0);
    if (idx + 3 < n) {
        c = *reinterpret_cast<const int4*>(cnt + idx);
    } else if (idx < n) {
        c.x = cnt[idx];
        if (idx + 1 < n) c.y = cnt[idx + 1];
        if (idx + 2 < n) c.z = cnt[idx + 2];
        if (idx + 3 < n) c.w = cnt[idx + 3];
    }
    if (idx + 0 < n) dinv[idx + 0] = rsqrtf((float)(c.x + 1));
    if (idx + 1 < n) dinv[idx + 1] = rsqrtf((float)(c.y + 1));
    if (idx + 2 < n) dinv[idx + 2] = rsqrtf((float)(c.z + 1));
    if (idx + 3 < n) dinv[idx + 3] = rsqrtf((float)(c.w + 1));

    const int s4 = c.x + c.y + c.z + c.w;
    const int incl = wave_incl_scan(s4, lane);
    if (lane == 63) swave[w] = incl;
    __syncthreads();
    int base = incl - s4;
    #pragma unroll
    for (int j = 0; j < 4; ++j) if (j < w) base += swave[j];

    if (idx + 3 < n) {
        int4 o;
        o.x = base;
        o.y = base + c.x;
        o.z = base + c.x + c.y;
        o.w = base + c.x + c.y + c.z;
        *reinterpret_cast<int4*>(rowstart + idx) = o;
    } else if (idx < n) {
        int acc = base;
        rowstart[idx] = acc; acc += c.x;
        if (idx + 1 < n) { rowstart[idx + 1] = acc; acc += c.y; }
        if (idx + 2 < n) { rowstart[idx + 2] = acc; acc += c.z; }
        if (idx + 3 < n) { rowstart[idx + 3] = acc; }
    }

    if (tid == 0) {
        int tot = swave[0] + swave[1] + swave[2] + swave[3];
        blocksum[blockIdx.x] = tot;
        if (blockIdx.x == gridDim.x - 1) rowstart[n] = tot;  // block-local end
        __threadfence();
        amLast = (atomicAdd(ticket, 1) == (int)gridDim.x - 1);
    }
    __syncthreads();
    if (amLast && tid < 64) {
        __threadfence();
        volatile int* bs = blocksum;
        const int nb = gridDim.x;
        int v = (tid < nb) ? bs[tid] : 0;
        int incl2 = wave_incl_scan(v, tid);
        if (tid < nb) blockoff[tid] = incl2 - v;
    }
}

// Grid-split kernel: blocks [0,nfb) do atomic-free CSR fill (4 edges/thread);
// blocks [nfb,..) do MFMA gemm1: h1b[i] = bf16( dinv[i] * (x[i] @ W1) ).
__global__ __launch_bounds__(256) void k_fillgemm1(
    const int* __restrict__ src, const int* __restrict__ dst,
    const int* __restrict__ slot, int e, int nfb,
    const int* __restrict__ rowstart, const int* __restrict__ blockoff,
    unsigned short* __restrict__ nbr,
    const float* __restrict__ x, const float* __restrict__ W,
    const float* __restrict__ dinv, unsigned short* __restrict__ h1b, int n) {
    __shared__ short wf[8 * 4 * 64 * 8];   // 32 KiB (gemm path only)
    if (blockIdx.x < nfb) {
        int i = blockIdx.x * 256 + threadIdx.x;
        int base = i * 4;
        if (base >= e) return;
        if (base + 3 < e) {
            int4 d4 = *reinterpret_cast<const int4*>(dst + base);
            int4 s4 = *reinterpret_cast<const int4*>(src + base);
            int4 t4 = *reinterpret_cast<const int4*>(slot + base);
            nbr[rowstart[d4.x] + blockoff[d4.x >> 10] + t4.x] = (unsigned short)s4.x;
            nbr[rowstart[d4.y] + blockoff[d4.y >> 10] + t4.y] = (unsigned short)s4.y;
            nbr[rowstart[d4.z] + blockoff[d4.z >> 10] + t4.z] = (unsigned short)s4.z;
            nbr[rowstart[d4.w] + blockoff[d4.w >> 10] + t4.w] = (unsigned short)s4.w;
        } else {
            for (int q = base; q < e; ++q) {
                int d = dst[q];
                nbr[rowstart[d] + blockoff[d >> 10] + slot[q]] = (unsigned short)src[q];
            }
        }
        return;
    }
    // ---- gemm1 path ----
    const int tid = threadIdx.x;
    for (int i = tid; i < 2048; i += 256) {
        const int l = i & 63, kt = (i >> 6) & 3, ct = i >> 8;
        const int krow = kt * 32 + ((l >> 4) << 3);
        const int col  = ct * 16 + (l & 15);
        const float* wp = W + (size_t)krow * C_HID + col;
        uint4 u;
        u.x = bpack(wp[0 * C_HID], wp[1 * C_HID]);
        u.y = bpack(wp[2 * C_HID], wp[3 * C_HID]);
        u.z = bpack(wp[4 * C_HID], wp[5 * C_HID]);
        u.w = bpack(wp[6 * C_HID], wp[7 * C_HID]);
        reinterpret_cast<uint4*>(wf)[i] = u;
    }
    __syncthreads();

    const int l = tid & 63, w = tid >> 6;
    const int row0 = (blockIdx.x - nfb) * 64 + w * 16;
    int arow = row0 + (l & 15);
    if (arow >= n) arow = n - 1;
    const float* xr = x + (size_t)arow * C_IN + ((l >> 4) << 3);

    bf8 a[4];
    #pragma unroll
    for (int kt = 0; kt < 4; ++kt) {
        float4 p0 = *reinterpret_cast<const float4*>(xr + kt * 32);
        float4 p1 = *reinterpret_cast<const float4*>(xr + kt * 32 + 4);
        bf8 t;
        t[0] = b16(p0.x); t[1] = b16(p0.y); t[2] = b16(p0.z); t[3] = b16(p0.w);
        t[4] = b16(p1.x); t[5] = b16(p1.y); t[6] = b16(p1.z); t[7] = b16(p1.w);
        a[kt] = t;
    }

    f32x4 acc[8];
    #pragma unroll
    for (int ct = 0; ct < 8; ++ct) acc[ct] = (f32x4){0.f, 0.f, 0.f, 0.f};
    const bf8* bw = reinterpret_cast<const bf8*>(wf);
    #pragma unroll
    for (int kt = 0; kt < 4; ++kt)
        #pragma unroll
        for (int ct = 0; ct < 8; ++ct)
            acc[ct] = __builtin_amdgcn_mfma_f32_16x16x32_bf16(
                a[kt], bw[(ct * 4 + kt) * 64 + l], acc[ct], 0, 0, 0);

    const int rbase = row0 + ((l >> 4) << 2);
    float dv[4];
    #pragma unroll
    for (int r = 0; r < 4; ++r) {
        int rr = rbase + r;
        dv[r] = (rr < n) ? dinv[rr] : 0.f;
    }
    #pragma unroll
    for (int ct = 0; ct < 8; ++ct) {
        const int col = ct * 16 + (l & 15);
        #pragma unroll
        for (int r = 0; r < 4; ++r) {
            int rr = rbase + r;
            if (rr < n)
                h1b[(size_t)rr * C_HID + col] = (unsigned short)b16(acc[ct][r] * dv[r]);
        }
    }
}

// Fused agg1 + gemm2, wave-local (NO cross-wave sync in the hot path).
// Each wave owns 16 nodes (one 16-row MFMA tile):
//   pass t=0,1: 8 nodes, 8 lanes/node, gather h1b rows (2 interleaved uint4
//   chunks/lane), relu+bias+dinv -> bf16 -> per-wave LDS act tile (4 KB).
//   Then 16 MFMA (16x64 tile, K=128) vs LDS-staged W2; h2b = bf16(dinv * .).
// Same-wave ds_write -> ds_read ordering is guaranteed by lgkmcnt; no
// __syncthreads couples different nodes' degree variance (R5/R12 lesson).
__global__ __launch_bounds__(256) void k_aggmm2(
    const uint4* __restrict__ h1v,          // [n][16] uint4 = 128 bf16/row
    const int* __restrict__ rowstart, const int* __restrict__ blockoff,
    const unsigned short* __restrict__ nbr,
    const float* __restrict__ dinv, const float* __restrict__ b1,
    const float* __restrict__ W2,
    unsigned short* __restrict__ h2b, int n) {
    __shared__ short wf[4 * 4 * 64 * 8];    // 16 KiB W2 frags
    __shared__ uint4 actl[4][16][16];       // 16 KiB act tiles (one per wave)
    const int tid = threadIdx.x;

    for (int i = tid; i < 1024; i += 256) {
        const int l = i & 63, kt = (i >> 6) & 3, ct = i >> 8;
        const int krow = kt * 32 + ((l >> 4) << 3);
        const int col  = ct * 16 + (l & 15);
        const float* wp = W2 + (size_t)krow * C_OUT + col;
        uint4 u;
        u.x = bpack(wp[0 * C_OUT], wp[1 * C_OUT]);
        u.y = bpack(wp[2 * C_OUT], wp[3 * C_OUT]);
        u.z = bpack(wp[4 * C_OUT], wp[5 * C_OUT]);
        u.w = bpack(wp[6 * C_OUT], wp[7 * C_OUT]);
        reinterpret_cast<uint4*>(wf)[i] = u;
    }
    __syncthreads();   // once, uniform (W2 staging only)

    const int l = tid & 63, wid = tid >> 6;
    const int u = blockIdx.x * 4 + wid;     // 16-node unit, one per wave
    const int node0 = u * 16;
    if (node0 >= n) return;
    const float4* b1f4 = reinterpret_cast<const float4*>(b1);

    // ---- gather passes: 8 nodes each, 8 lanes/node, chunks p2 and p2+8 ----
    const int p2 = l & 7;
    #pragma unroll
    for (int t = 0; t < 2; ++t) {
        const int g    = t * 8 + (l >> 3);
        const int node = node0 + g;
        uint4 pk0 = make_uint4(0, 0, 0, 0), pk1 = make_uint4(0, 0, 0, 0);
        if (node < n) {
            float a16[16];
            #pragma unroll
            for (int q = 0; q < 16; ++q) a16[q] = 0.f;
            const uint4* self = h1v + (size_t)node * 16 + p2;
            acc8(a16 + 0, self[0]);
            acc8(a16 + 8, self[8]);
            int j   = rowstart[node]     + blockoff[node >> 10];
            int end = rowstart[node + 1] + blockoff[(node + 1) >> 10];
            for (; j + 1 < end; j += 2) {
                int s0 = nbr[j], s1 = nbr[j + 1];
                const uint4* r0 = h1v + (size_t)s0 * 16 + p2;
                const uint4* r1 = h1v + (size_t)s1 * 16 + p2;
                uint4 v00 = r0[0], v01 = r0[8];
                uint4 v10 = r1[0], v11 = r1[8];
                acc8(a16 + 0, v00); acc8(a16 + 8, v01);
                acc8(a16 + 0, v10); acc8(a16 + 8, v11);
            }
            if (j < end) {
                const uint4* r0 = h1v + (size_t)nbr[j] * 16 + p2;
                acc8(a16 + 0, r0[0]); acc8(a16 + 8, r0[8]);
            }
            const float sc = dinv[node];
            // chunk c = p2 covers ch p2*8..p2*8+7 (bias float4 idx 2c, 2c+1)
            float4 ba = b1f4[2 * p2 + 0],  bbv = b1f4[2 * p2 + 1];
            pk0.x = bpack(fmaxf(sc * a16[0] + ba.x, 0.f),  fmaxf(sc * a16[1] + ba.y, 0.f));
            pk0.y = bpack(fmaxf(sc * a16[2] + ba.z, 0.f),  fmaxf(sc * a16[3] + ba.w, 0.f));
            pk0.z = bpack(fmaxf(sc * a16[4] + bbv.x, 0.f), fmaxf(sc * a16[5] + bbv.y, 0.f));
            pk0.w = bpack(fmaxf(sc * a16[6] + bbv.z, 0.f), fmaxf(sc * a16[7] + bbv.w, 0.f));
            // chunk c = p2+8
            float4 bc = b1f4[2 * (p2 + 8) + 0], bd = b1f4[2 * (p2 + 8) + 1];
            pk1.x = bpack(fmaxf(sc * a16[8]  + bc.x, 0.f), fmaxf(sc * a16[9]  + bc.y, 0.f));
            pk1.y = bpack(fmaxf(sc * a16[10] + bc.z, 0.f), fmaxf(sc * a16[11] + bc.w, 0.f));
            pk1.z = bpack(fmaxf(sc * a16[12] + bd.x, 0.f), fmaxf(sc * a16[13] + bd.y, 0.f));
            pk1.w = bpack(fmaxf(sc * a16[14] + bd.z, 0.f), fmaxf(sc * a16[15] + bd.w, 0.f));
        }
        actl[wid][g][p2]     = pk0;
        actl[wid][g][p2 + 8] = pk1;
    }

    // ---- MFMA phase (same wave; lgkmcnt orders LDS RAW) ----
    bf8 a[4];
    #pragma unroll
    for (int kt = 0; kt < 4; ++kt) {
        uint4 av = actl[wid][l & 15][kt * 4 + (l >> 4)];
        a[kt] = *reinterpret_cast<bf8*>(&av);
    }
    f32x4 acc[4];
    #pragma unroll
    for (int ct = 0; ct < 4; ++ct) acc[ct] = (f32x4){0.f, 0.f, 0.f, 0.f};
    const bf8* bw = reinterpret_cast<const bf8*>(wf);
    #pragma unroll
    for (int kt = 0; kt < 4; ++kt)
        #pragma unroll
        for (int ct = 0; ct < 4; ++ct)
            acc[ct] = __builtin_amdgcn_mfma_f32_16x16x32_bf16(
                a[kt], bw[(ct * 4 + kt) * 64 + l], acc[ct], 0, 0, 0);

    const int rbase = node0 + ((l >> 4) << 2);
    float dv[4];
    #pragma unroll
    for (int r = 0; r < 4; ++r) {
        int rr = rbase + r;
        dv[r] = (rr < n) ? dinv[rr] : 0.f;
    }
    #pragma unroll
    for (int ct = 0; ct < 4; ++ct) {
        const int col = ct * 16 + (l & 15);
        #pragma unroll
        for (int r = 0; r < 4; ++r) {
            int rr = rbase + r;
            if (rr < n)
                h2b[(size_t)rr * C_OUT + col] = (unsigned short)b16(acc[ct][r] * dv[r]);
        }
    }
}

// out[i] = dinv[i]*(h2[i] + sum nbr h2) + b2   (8 thr/node, uint4 gathers)
__global__ __launch_bounds__(256) void k_agg2b(const uint4* __restrict__ h2v,
                                               const int* __restrict__ rowstart,
                                               const int* __restrict__ blockoff,
                                               const unsigned short* __restrict__ nbr,
                                               const float* __restrict__ dinv,
                                               const float* __restrict__ b2,
                                               float* __restrict__ outb, int n) {
    int node = blockIdx.x * 32 + (threadIdx.x >> 3);
    if (node >= n) return;
    const int lane8 = threadIdx.x & 7;
    float a8[8] = {0.f, 0.f, 0.f, 0.f, 0.f, 0.f, 0.f, 0.f};
    acc8(a8, h2v[(size_t)node * 8 + lane8]);         // self loop
    int j   = rowstart[node]     + blockoff[node >> 10];
    int end = rowstart[node + 1] + blockoff[(node + 1) >> 10];
    for (; j + 1 < end; j += 2) {
        int s0 = nbr[j], s1 = nbr[j + 1];
        uint4 v0 = h2v[(size_t)s0 * 8 + lane8];
        uint4 v1 = h2v[(size_t)s1 * 8 + lane8];
        acc8(a8, v0); acc8(a8, v1);
    }
    if (j < end) acc8(a8, h2v[(size_t)nbr[j] * 8 + lane8]);
    const float s = dinv[node];
    const float4 c0 = reinterpret_cast<const float4*>(b2)[2 * lane8 + 0];
    const float4 c1 = reinterpret_cast<const float4*>(b2)[2 * lane8 + 1];
    float4 o0, o1;
    o0.x = s * a8[0] + c0.x; o0.y = s * a8[1] + c0.y;
    o0.z = s * a8[2] + c0.z; o0.w = s * a8[3] + c0.w;
    o1.x = s * a8[4] + c1.x; o1.y = s * a8[5] + c1.y;
    o1.z = s * a8[6] + c1.z; o1.w = s * a8[7] + c1.w;
    reinterpret_cast<float4*>(outb)[node * 16 + 2 * lane8 + 0] = o0;
    reinterpret_cast<float4*>(outb)[node * 16 + 2 * lane8 + 1] = o1;
}

extern "C" void kernel_launch(void* const* d_in, const int* in_sizes, int n_in,
                              void* d_out, int out_size, void* d_ws, size_t ws_size,
                              hipStream_t stream) {
    const float* x  = (const float*)d_in[0];
    const int*   ei = (const int*)d_in[1];
    const float* W1 = (const float*)d_in[2];
    const float* b1 = (const float*)d_in[3];
    const float* W2 = (const float*)d_in[4];
    const float* b2 = (const float*)d_in[5];

    const int n = in_sizes[0] / C_IN;   // 50000 (<=65536: u16 nbr, 2-level scan)
    const int e = in_sizes[1] / 2;      // 800000
    const int* src = ei;
    const int* dst = ei + e;

    // Workspace layout (non-overlapping):
    //   [0, 256K)      dinv ; [256K, 512K) cnt (+ticket at cnt[n])
    //   [512K, 768K)   rowstart (n+1, padded)
    //   [768K, +4K)    blocksum ; [772K, +4K) blockoff
    //   [1M, 4.2M)     slot ; [5M, 6.6M) nbr (u16)
    //   [8M, 20.8M)    h1b ; [21M, 27.4M) h2b
    char* ws = (char*)d_ws;
    float* dinv     = (float*)(ws);
    int*   cnt      = (int*)  (ws + (1u << 18));
    int*   rowstart = (int*)  (ws + (2u << 18));
    int*   blocksum = (int*)  (ws + (3u << 18));
    int*   blockoff = (int*)  (ws + (3u << 18) + 4096);
    int*   slot     = (int*)  (ws + (1u << 20));
    unsigned short* nbr = (unsigned short*)(ws + (5u << 20));
    unsigned short* h1b = (unsigned short*)(ws + (8u << 20));
    unsigned short* h2b = (unsigned short*)(ws + (21u << 20));
    int*   ticket   = cnt + n;
    float* outb     = (float*)d_out;

    const int NB  = (n + 1023) / 1024;           // 49 <= 64
    const int nz4 = (n + 1 + 3) / 4;             // cnt + ticket
    const int nFB = ((e + 3) / 4 + 255) / 256;   // fill blocks
    const int nGB = (n + 63) / 64;               // gemm1 blocks
    const int nU  = (n + 15) / 16;               // 16-node units
    const int nAB = (nU + 3) / 4;                // aggmm2 blocks (4 waves ea.)

    k_zero     <<<(nz4 + 255) / 256, 256, 0, stream>>>(cnt, nz4);
    k_count2   <<<nFB, 256, 0, stream>>>(dst, e, cnt, slot);
    k_scanAB   <<<NB, 256, 0, stream>>>(cnt, n, rowstart, blocksum, blockoff, ticket, dinv);
    k_fillgemm1<<<nFB + nGB, 256, 0, stream>>>(src, dst, slot, e, nFB, rowstart, blockoff,
                                               nbr, x, W1, dinv, h1b, n);
    k_aggmm2   <<<nAB, 256, 0, stream>>>((const uint4*)h1b, rowstart, blockoff, nbr,
                                         dinv, b1, W2, h2b, n);
    k_agg2b    <<<(n + 31) / 32, 256, 0, stream>>>((const uint4*)h2b, rowstart, blockoff, nbr,
                                                   dinv, b2, outb, n);
}